// Round 6
// baseline (410.275 us; speedup 1.0000x reference)
//
#include <hip/hip_runtime.h>

typedef __attribute__((ext_vector_type(8))) short   short8;
typedef __attribute__((ext_vector_type(8))) __bf16  bf16x8;
typedef __attribute__((ext_vector_type(4))) float   f32x4;

#define NSTEPS 49

static __device__ __forceinline__ short8 as_s8(bf16x8 v) {
    return __builtin_bit_cast(short8, v);
}

#define MFMA(A, B, C) __builtin_amdgcn_mfma_f32_16x16x32_bf16((A), (B), (C), 0, 0, 0)

// Weight fragment LDS layout (same as R5):
//   L1 unit U0..U3: frags 6u..6u+5 (tiles 2u,2u+1 x 3 slices; slice2=[t,bias])
//   L2 unit U4..U7: frags 24+8(u-4)..+7
//   L3 unit U8..U9: frags 56+8(u-8).. +7
#define NFRAG 72

// Laundered-base LDS frag read (fz == 0 but opaque per eval: blocks cross-eval
// CSE that would hoist 288 regs of weights and recreate the R1-R3 spills).
#define LW(IDX) (Wlds[fz + (unsigned)(IDX)][lane])

// ---- bank machinery: 3 rotating 8-frag register banks (depth-2 pipeline) ----
#define LDF(P, I, F0) P##I = LW((F0) + I);
#define LD6(P, F0) { LDF(P,0,F0) LDF(P,1,F0) LDF(P,2,F0) LDF(P,3,F0)         \
                     LDF(P,4,F0) LDF(P,5,F0) }
#define LD8(P, F0) { LD6(P, F0) LDF(P,6,F0) LDF(P,7,F0) }

#define RELU_PACK(AA, AB, OUT)                                               \
    {                                                                        \
        bf16x8 v_;                                                           \
        v_[0]=(__bf16)fmaxf((AA)[0],0.f); v_[1]=(__bf16)fmaxf((AA)[1],0.f);  \
        v_[2]=(__bf16)fmaxf((AA)[2],0.f); v_[3]=(__bf16)fmaxf((AA)[3],0.f);  \
        v_[4]=(__bf16)fmaxf((AB)[0],0.f); v_[5]=(__bf16)fmaxf((AB)[1],0.f);  \
        v_[6]=(__bf16)fmaxf((AB)[2],0.f); v_[7]=(__bf16)fmaxf((AB)[3],0.f);  \
        OUT = as_s8(v_);                                                     \
    }

#define L1U(P, OUT)                                                          \
    {                                                                        \
        f32x4 aA_ = MFMA(P##0, xs0, zz); aA_ = MFMA(P##1, xs1, aA_);         \
        aA_ = MFMA(P##2, xt, aA_);                                           \
        f32x4 aB_ = MFMA(P##3, xs0, zz); aB_ = MFMA(P##4, xs1, aB_);         \
        aB_ = MFMA(P##5, xt, aB_);                                           \
        RELU_PACK(aA_, aB_, OUT);                                            \
    }

#define L2U(P, CA, CB, OUT)                                                  \
    {                                                                        \
        f32x4 aA_ = MFMA(P##0, xh0, CA); aA_ = MFMA(P##1, xh1, aA_);         \
        aA_ = MFMA(P##2, xh2, aA_);      aA_ = MFMA(P##3, xh3, aA_);         \
        f32x4 aB_ = MFMA(P##4, xh0, CB); aB_ = MFMA(P##5, xh1, aB_);         \
        aB_ = MFMA(P##6, xh2, aB_);      aB_ = MFMA(P##7, xh3, aB_);         \
        RELU_PACK(aA_, aB_, OUT);                                            \
    }

#define L3U(P, CA, CB, OA, OB)                                               \
    {                                                                        \
        f32x4 aA_ = MFMA(P##0, xg0, CA); aA_ = MFMA(P##1, xg1, aA_);         \
        aA_ = MFMA(P##2, xg2, aA_);      aA_ = MFMA(P##3, xg3, aA_);         \
        f32x4 aB_ = MFMA(P##4, xg0, CB); aB_ = MFMA(P##5, xg1, aB_);         \
        aB_ = MFMA(P##6, xg2, aB_);      aB_ = MFMA(P##7, xg3, aB_);         \
        OA = aA_; OB = aB_;                                                  \
    }

// Depth-2 software pipeline: unit i+2's ds_reads issue before unit i's MFMAs
// (~120+ cyc prefetch distance >= LDS latency). Banks rotate X->Y->Z with
// period 3; 6 evals/step => stationary across steps. On entry: U0 in BX,
// U1 in BY (loaded by predecessor's tail). Exit: next U0 in BY, U1 in BZ.
#define MLP_EVAL3(BX, BY, BZ, KV)                                            \
    {                                                                        \
        const f32x4 zz = {0.f, 0.f, 0.f, 0.f};                               \
        short8 xh0, xh1, xh2, xh3, xg0, xg1, xg2, xg3;                       \
        LD6(BZ, 12) L1U(BX, xh0)                                             \
        LD6(BX, 18) L1U(BY, xh1)                                             \
        LD8(BY, 24) L1U(BZ, xh2)                                             \
        LD8(BZ, 32) L1U(BX, xh3)                                             \
        LD8(BX, 40) L2U(BY, bL2v[0], bL2v[1], xg0)                           \
        LD8(BY, 48) L2U(BZ, bL2v[2], bL2v[3], xg1)                           \
        LD8(BZ, 56) L2U(BX, bL2v[4], bL2v[5], xg2)                           \
        LD8(BX, 64) L2U(BY, bL2v[6], bL2v[7], xg3)                           \
        asm volatile("" : "+v"(fz));                                         \
        LD6(BY, 0)  L3U(BZ, bL3v[0], bL3v[1], KV[0], KV[1])                  \
        LD6(BZ, 6)  L3U(BX, bL3v[2], bL3v[3], KV[2], KV[3])                  \
    }

// xs slices from f32x4 SRC[4]: slice0[j] = SRC[j>>2][j&3], slice1[j] = SRC[(j>>2)+2][j&3]
#define BUILD_XS(SRC)                                                        \
    {                                                                        \
        bf16x8 v0_, v1_;                                                     \
        _Pragma("unroll")                                                    \
        for (int j_ = 0; j_ < 8; ++j_) {                                     \
            v0_[j_] = (__bf16)(SRC)[j_ >> 2][j_ & 3];                        \
            v1_[j_] = (__bf16)(SRC)[(j_ >> 2) + 2][j_ & 3];                  \
        }                                                                    \
        xs0 = as_s8(v0_); xs1 = as_s8(v1_);                                  \
    }

// Third L1 K-slice: k=64 carries t, k=65 carries constant 1.0 (bias column).
#define BUILD_XT(TV)                                                         \
    {                                                                        \
        bf16x8 v_;                                                           \
        _Pragma("unroll") for (int j_ = 0; j_ < 8; ++j_) v_[j_] = (__bf16)0.f; \
        if (q == 0) { v_[0] = (__bf16)(TV); v_[1] = (__bf16)1.0f; }          \
        xt = as_s8(v_);                                                      \
    }

// Store fresh f32 k (f32x4[4]) as packed bf16 in xs-slice order (4 VGPRs).
#define STORE_KB(KB, KV)                                                     \
    {                                                                        \
        bf16x8 t0_, t1_;                                                     \
        _Pragma("unroll")                                                    \
        for (int j_ = 0; j_ < 8; ++j_) {                                     \
            t0_[j_] = (__bf16)(KV)[j_ >> 2][j_ & 3];                         \
            t1_[j_] = (__bf16)(KV)[(j_ >> 2) + 2][j_ & 3];                   \
        }                                                                    \
        (KB)[0] = t0_; (KB)[1] = t1_;                                        \
    }

// Unpack one bf16 k value (V = 0..15, compile-time in unrolled loops).
#define KF(KB, V) ((float)(KB)[(V) >> 3][(V) & 7])

// One wave per block owns 16 batch rows and the entire MLP. Weights stream
// from LDS through a depth-2, 3-bank register pipeline. Stage inputs are
// reassociated as si = pre + (dt*a_{s+1,s})*kv with pre (old-k terms only)
// computed BEFORE the eval, so the post-eval critical path is 1 FMA + 1 cvt.
// Zero barriers in the loop, zero shuffles.
extern "C" __global__ void __launch_bounds__(64, 1)
node_solve(const float* __restrict__ y0, const float* __restrict__ ts,
           const float* __restrict__ gw0, const float* __restrict__ gb0,
           const float* __restrict__ gw1, const float* __restrict__ gb1,
           const float* __restrict__ gw2, const float* __restrict__ gb2,
           float* __restrict__ out)
{
    __shared__ short8 Wlds[NFRAG][64];   // 72 KiB

    const int lane = threadIdx.x & 63;
    const int q    = lane >> 4;
    const int c    = lane & 15;
    const int row0 = blockIdx.x << 4;

    // ---- stage weights into LDS as K-permuted per-lane A-frags ----
    // perm: k-position 32ks+8q+j  <-  source column 32ks+16*(j>>2)+4q+(j&3)
    for (int t = 0; t < 8; ++t) {
        const int n = 16 * t + c;
        const float* w0r = gw0 + n * 65 + 1;      // col 0 of gw0 is the t-weight
        for (int ks = 0; ks < 2; ++ks) {
            bf16x8 v;
            #pragma unroll
            for (int j = 0; j < 8; ++j)
                v[j] = (__bf16)w0r[32*ks + 16*(j>>2) + 4*q + (j&3)];
            Wlds[t*3 + ks][lane] = as_s8(v);
        }
        {
            bf16x8 v;
            #pragma unroll
            for (int j = 0; j < 8; ++j) v[j] = (__bf16)0.f;
            if (q == 0) { v[0] = (__bf16)gw0[n*65]; v[1] = (__bf16)gb0[n]; }
            Wlds[t*3 + 2][lane] = as_s8(v);
        }
        const float* w1r = gw1 + n * 128;
        for (int ks = 0; ks < 4; ++ks) {
            bf16x8 v;
            #pragma unroll
            for (int j = 0; j < 8; ++j)
                v[j] = (__bf16)w1r[32*ks + 16*(j>>2) + 4*q + (j&3)];
            Wlds[24 + t*4 + ks][lane] = as_s8(v);
        }
    }
    for (int t = 0; t < 4; ++t) {
        const int n = 16 * t + c;
        const float* w2r = gw2 + n * 128;
        for (int ks = 0; ks < 4; ++ks) {
            bf16x8 v;
            #pragma unroll
            for (int j = 0; j < 8; ++j)
                v[j] = (__bf16)w2r[32*ks + 16*(j>>2) + 4*q + (j&3)];
            Wlds[56 + t*4 + ks][lane] = as_s8(v);
        }
    }
    __syncthreads();   // single wave: once, before the loop

    // ---- resident biases (C-operand init vectors), layout b[16t+4q+r] ----
    f32x4 bL2v[8], bL3v[4];
    #pragma unroll
    for (int t = 0; t < 8; ++t) bL2v[t] = *(const f32x4*)(gb1 + 16*t + 4*q);
    #pragma unroll
    for (int t = 0; t < 4; ++t) bL3v[t] = *(const f32x4*)(gb2 + 16*t + 4*q);

    // ---- persistent state: yn[t][r] = y[row0+c][16t+4q+r] (running 5th-order sum) ----
    f32x4 yn[4];
    #pragma unroll
    for (int t = 0; t < 4; ++t)
        yn[t] = *(const f32x4*)(y0 + (size_t)(row0 + c) * 64 + 16*t + 4*q);

    const float ts0 = ts[0];
    const float dtv = ts[1] - ts[0];

    // dt-scaled b-weights, reparametrized g_sj = dt*(a_sj - b_j), and
    // post-eval stage-input coefficients h_s = dt*a_{s+1,s}.
    const float e1 = dtv * 0.09646076681806523f, e2 = dtv * 0.01f;
    const float e3 = dtv * 0.4798896504144996f,  e4 = dtv * 1.379008574103742f;
    const float e5 = dtv * -3.290069515436081f,  e6 = dtv * 2.324710524099774f;
    const float h1 = dtv * 0.161f;
    const float h2 = dtv * 0.335480655492357f;
    const float h3 = dtv * 4.3622954328695815f;
    const float h4 = dtv * -0.09249506636175525f;
    const float h5 = dtv * -0.028269050394068383f;
    const float g31 = dtv * (-0.008480655492356989f - 0.09646076681806523f);
    const float g41 = dtv * (2.8971530571054935f    - 0.09646076681806523f);
    const float g42 = dtv * (-6.359448489975075f    - 0.01f);
    const float g51 = dtv * (5.325864828439257f     - 0.09646076681806523f);
    const float g52 = dtv * (-11.748883564062828f   - 0.01f);
    const float g53 = dtv * (7.4955393428898365f    - 0.4798896504144996f);
    const float g61 = dtv * (5.86145544294642f      - 0.09646076681806523f);
    const float g62 = dtv * (-12.92096931784711f    - 0.01f);
    const float g63 = dtv * (8.159367898576159f     - 0.4798896504144996f);
    const float g64 = dtv * (-0.071584973281401f    - 1.379008574103742f);

    short8 xs0, xs1, xt;
    short8 bA0, bA1, bA2, bA3, bA4, bA5, bA6, bA7;
    short8 bB0, bB1, bB2, bB3, bB4, bB5, bB6, bB7;
    short8 bC0, bC1, bC2, bC3, bC4, bC5, bC6, bC7;
    unsigned fz = 0;   // laundered per MLP eval; always 0, provably unknowable

    // prologue: preload eval 1's U0 (bank A) and U1 (bank B)
    asm volatile("" : "+v"(fz));
    LD6(bA, 0) LD6(bB, 6)

    #pragma unroll 1
    for (int step = 0; step < NSTEPS; ++step) {
        const float t0s = ts0 + (float)step * dtv;
        f32x4 kv[4], si[4], pre[4];
        bf16x8 kb0[2], kb1[2], kb2[2], kb3[2];

        // ---- stage 1 ----
        BUILD_XS(yn); BUILD_XT(t0s);
        #pragma unroll
        for (int t = 0; t < 4; ++t) pre[t] = yn[t];                 // pre for si2
        MLP_EVAL3(bA, bB, bC, kv)
        #pragma unroll
        for (int t = 0; t < 4; ++t) yn[t] += e1 * kv[t];
        STORE_KB(kb0, kv);
        #pragma unroll
        for (int t = 0; t < 4; ++t) si[t] = pre[t] + h1 * kv[t];
        BUILD_XS(si); BUILD_XT(t0s + 0.161f * dtv);

        // ---- stage 2 ----
        #pragma unroll
        for (int v = 0; v < 16; ++v)                                 // pre for si3
            pre[v>>2][v&3] = yn[v>>2][v&3] + g31*KF(kb0,v);
        MLP_EVAL3(bB, bC, bA, kv)
        #pragma unroll
        for (int t = 0; t < 4; ++t) yn[t] += e2 * kv[t];
        STORE_KB(kb1, kv);
        #pragma unroll
        for (int t = 0; t < 4; ++t) si[t] = pre[t] + h2 * kv[t];
        BUILD_XS(si); BUILD_XT(t0s + 0.327f * dtv);

        // ---- stage 3 ----
        #pragma unroll
        for (int v = 0; v < 16; ++v)                                 // pre for si4
            pre[v>>2][v&3] = yn[v>>2][v&3] + g41*KF(kb0,v) + g42*KF(kb1,v);
        MLP_EVAL3(bC, bA, bB, kv)
        #pragma unroll
        for (int t = 0; t < 4; ++t) yn[t] += e3 * kv[t];
        STORE_KB(kb2, kv);
        #pragma unroll
        for (int t = 0; t < 4; ++t) si[t] = pre[t] + h3 * kv[t];
        BUILD_XS(si); BUILD_XT(t0s + 0.9f * dtv);

        // ---- stage 4 ----
        #pragma unroll
        for (int v = 0; v < 16; ++v)                                 // pre for si5
            pre[v>>2][v&3] = yn[v>>2][v&3] + g51*KF(kb0,v) + g52*KF(kb1,v)
                           + g53*KF(kb2,v);
        MLP_EVAL3(bA, bB, bC, kv)
        #pragma unroll
        for (int t = 0; t < 4; ++t) yn[t] += e4 * kv[t];
        STORE_KB(kb3, kv);
        #pragma unroll
        for (int t = 0; t < 4; ++t) si[t] = pre[t] + h4 * kv[t];
        BUILD_XS(si); BUILD_XT(t0s + 0.9800255409045097f * dtv);

        // ---- stage 5 ----
        #pragma unroll
        for (int v = 0; v < 16; ++v)                                 // pre for si6
            pre[v>>2][v&3] = yn[v>>2][v&3] + g61*KF(kb0,v) + g62*KF(kb1,v)
                           + g63*KF(kb2,v) + g64*KF(kb3,v);
        MLP_EVAL3(bB, bC, bA, kv)
        #pragma unroll
        for (int t = 0; t < 4; ++t) yn[t] += e5 * kv[t];
        #pragma unroll
        for (int t = 0; t < 4; ++t) si[t] = pre[t] + h5 * kv[t];
        BUILD_XS(si); BUILD_XT(t0s + dtv);

        // ---- stage 6 ----
        MLP_EVAL3(bC, bA, bB, kv)
        #pragma unroll
        for (int t = 0; t < 4; ++t) yn[t] += e6 * kv[t];
    }

    #pragma unroll
    for (int t = 0; t < 4; ++t)
        *(f32x4*)(out + (size_t)(row0 + c) * 64 + 16*t + 4*q) = yn[t];
}

extern "C" void kernel_launch(void* const* d_in, const int* in_sizes, int n_in,
                              void* d_out, int out_size, void* d_ws, size_t ws_size,
                              hipStream_t stream) {
    const float* y0 = (const float*)d_in[0];
    const float* ts = (const float*)d_in[1];
    const float* w0 = (const float*)d_in[2];
    const float* b0 = (const float*)d_in[3];
    const float* w1 = (const float*)d_in[4];
    const float* b1 = (const float*)d_in[5];
    const float* w2 = (const float*)d_in[6];
    const float* b2 = (const float*)d_in[7];
    float* out = (float*)d_out;

    node_solve<<<dim3(128), dim3(64), 0, stream>>>(y0, ts, w0, b0, w1, b1, w2, b2, out);
}

// Round 7
// 244.366 us; speedup vs baseline: 1.6789x; 1.6789x over previous
//
#include <hip/hip_runtime.h>

typedef __attribute__((ext_vector_type(8))) short   short8;
typedef __attribute__((ext_vector_type(8))) __bf16  bf16x8;
typedef __attribute__((ext_vector_type(4))) __bf16  bf16x4;
typedef __attribute__((ext_vector_type(4))) float   f32x4;
typedef __attribute__((ext_vector_type(4))) unsigned short ushort4v;

#define NSTEPS 49

static __device__ __forceinline__ short8 as_s8(bf16x8 v) {
    return __builtin_bit_cast(short8, v);
}
static __device__ __forceinline__ bf16x4 pack4(f32x4 v) {
    bf16x4 b;
    b[0] = (__bf16)v[0]; b[1] = (__bf16)v[1];
    b[2] = (__bf16)v[2]; b[3] = (__bf16)v[3];
    return b;
}

#define MFMA(A, B, C) __builtin_amdgcn_mfma_f32_16x16x32_bf16((A), (B), (C), 0, 0, 0)

// Third L1 K-slice: slot (q=0,j=0) carries t, (q=0,j=1) carries constant 1.0
// (bias column) — pairs with the [t,bias] weight fragment.
#define BUILD_XT(TV)                                                         \
    {                                                                        \
        bf16x8 v_;                                                           \
        _Pragma("unroll") for (int j_ = 0; j_ < 8; ++j_) v_[j_] = (__bf16)0.f; \
        if (q == 0) { v_[0] = (__bf16)(TV); v_[1] = (__bf16)1.0f; }          \
        xt = as_s8(v_);                                                      \
    }

#define RELU_PACK(AA, AB, OUT)                                               \
    {                                                                        \
        bf16x8 v_;                                                           \
        v_[0]=(__bf16)fmaxf((AA)[0],0.f); v_[1]=(__bf16)fmaxf((AA)[1],0.f);  \
        v_[2]=(__bf16)fmaxf((AA)[2],0.f); v_[3]=(__bf16)fmaxf((AA)[3],0.f);  \
        v_[4]=(__bf16)fmaxf((AB)[0],0.f); v_[5]=(__bf16)fmaxf((AB)[1],0.f);  \
        v_[6]=(__bf16)fmaxf((AB)[2],0.f); v_[7]=(__bf16)fmaxf((AB)[3],0.f);  \
        OUT = as_s8(v_);                                                     \
    }

// One full Tsit5 stage, 4-wave cooperative. Weights register-resident per
// wave (K-permuted so each wave's MFMA C-output IS its B-frag exchange
// slice). LDS used only for activation slices: slice-major [slice][lane]
// 16B/lane = conflict-free. 3 barriers/stage; state tail runs AFTER the
// last barrier (register-only) overlapping the next stage's reads.
#define STAGE(TN, HS)                                                        \
    {                                                                        \
        const f32x4 zz = {0.f, 0.f, 0.f, 0.f};                               \
        /* ---- P1: L1 (si -> h), tiles 2w, 2w+1 ---- */                     \
        short8 xs0 = *(const short8*)(&XS[0][lane][0]);                      \
        short8 xs1 = *(const short8*)(&XS[1][lane][0]);                      \
        short8 xt; BUILD_XT(TN);                                             \
        f32x4 aA = MFMA(wL1[0], xs0, zz); aA = MFMA(wL1[1], xs1, aA);        \
        aA = MFMA(wL1[2], xt, aA);                                           \
        f32x4 aB = MFMA(wL1[3], xs0, zz); aB = MFMA(wL1[4], xs1, aB);        \
        aB = MFMA(wL1[5], xt, aB);                                           \
        short8 xhm; RELU_PACK(aA, aB, xhm);                                  \
        *(short8*)(&XH[w][lane][0]) = xhm;                                   \
        __syncthreads();                                                     \
        /* ---- P2: L2 (h -> g), tiles 2w, 2w+1 ---- */                      \
        short8 xh0 = *(const short8*)(&XH[0][lane][0]);                      \
        short8 xh1 = *(const short8*)(&XH[1][lane][0]);                      \
        short8 xh2 = *(const short8*)(&XH[2][lane][0]);                      \
        short8 xh3 = *(const short8*)(&XH[3][lane][0]);                      \
        f32x4 gA = MFMA(wL2[0], xh0, bL2v[0]); gA = MFMA(wL2[1], xh1, gA);   \
        gA = MFMA(wL2[2], xh2, gA);            gA = MFMA(wL2[3], xh3, gA);   \
        f32x4 gB = MFMA(wL2[4], xh0, bL2v[1]); gB = MFMA(wL2[5], xh1, gB);   \
        gB = MFMA(wL2[6], xh2, gB);            gB = MFMA(wL2[7], xh3, gB);   \
        short8 xgm; RELU_PACK(gA, gB, xgm);                                  \
        *(short8*)(&XG[w][lane][0]) = xgm;                                   \
        __syncthreads();                                                     \
        /* ---- P3: L3 (g -> kv), tile w; si = pre + h*kv ---- */            \
        short8 xg0 = *(const short8*)(&XG[0][lane][0]);                      \
        short8 xg1 = *(const short8*)(&XG[1][lane][0]);                      \
        short8 xg2 = *(const short8*)(&XG[2][lane][0]);                      \
        short8 xg3 = *(const short8*)(&XG[3][lane][0]);                      \
        kv = MFMA(wL3[0], xg0, bL3v); kv = MFMA(wL3[1], xg1, kv);            \
        kv = MFMA(wL3[2], xg2, kv);   kv = MFMA(wL3[3], xg3, kv);            \
        _Pragma("unroll")                                                    \
        for (int r_ = 0; r_ < 4; ++r_) si[r_] = pre[r_] + (HS) * kv[r_];     \
        *(ushort4v*)(&XS[w >> 1][lane][4 * (w & 1)]) =                       \
            __builtin_bit_cast(ushort4v, pack4(si));                        \
        __syncthreads();                                                     \
    }

// 4 waves per block own 16 batch rows. Wave w holds L1 tiles 2w,2w+1
// (6 frags), L2 tiles 2w,2w+1 (8 frags), L3 tile w (4 frags) = 72 VGPRs of
// weights + the ODE state for dims [16w,16w+16) (4 f32/lane). This removes
// both the R1-R6 register-spill pressure (no 288-reg demand) AND the
// R4-R6 72KB/eval LDS weight stream (activation exchange is ~3KB/stage).
extern "C" __global__ void __launch_bounds__(256, 1)
node_solve(const float* __restrict__ y0, const float* __restrict__ ts,
           const float* __restrict__ gw0, const float* __restrict__ gb0,
           const float* __restrict__ gw1, const float* __restrict__ gb1,
           const float* __restrict__ gw2, const float* __restrict__ gb2,
           float* __restrict__ out)
{
    __shared__ __align__(16) unsigned short XS[2][64][8];  // stage-input slices
    __shared__ __align__(16) unsigned short XH[4][64][8];  // L1 output slices
    __shared__ __align__(16) unsigned short XG[4][64][8];  // L2 output slices

    const int tid  = threadIdx.x;
    const int w    = tid >> 6;      // wave 0..3
    const int lane = tid & 63;
    const int q    = lane >> 4;
    const int c    = lane & 15;
    const int row0 = blockIdx.x << 4;

    // ---- weights -> K-permuted register A-frags (this wave's tiles only) ----
    // perm: k-position (ks, q, j) <- source column 32ks+16*(j>>2)+4q+(j&3)
    short8 wL1[6];   // tiles 2w,2w+1 x slices {y0-31, y32-63, [t,bias]}
    short8 wL2[8];   // tiles 2w,2w+1 x 4 k-slices
    short8 wL3[4];   // tile w x 4 k-slices
    f32x4  bL2v[2], bL3v;

    #pragma unroll
    for (int p = 0; p < 2; ++p) {
        const int t = 2 * w + p;
        const int n = 16 * t + c;
        const float* w0r = gw0 + n * 65 + 1;      // col 0 of gw0 is the t-weight
        #pragma unroll
        for (int ks = 0; ks < 2; ++ks) {
            bf16x8 v;
            #pragma unroll
            for (int j = 0; j < 8; ++j)
                v[j] = (__bf16)w0r[32*ks + 16*(j>>2) + 4*q + (j&3)];
            wL1[3*p + ks] = as_s8(v);
        }
        {
            bf16x8 v;
            #pragma unroll
            for (int j = 0; j < 8; ++j) v[j] = (__bf16)0.f;
            if (q == 0) { v[0] = (__bf16)gw0[n*65]; v[1] = (__bf16)gb0[n]; }
            wL1[3*p + 2] = as_s8(v);
        }
        const float* w1r = gw1 + n * 128;
        #pragma unroll
        for (int ks = 0; ks < 4; ++ks) {
            bf16x8 v;
            #pragma unroll
            for (int j = 0; j < 8; ++j)
                v[j] = (__bf16)w1r[32*ks + 16*(j>>2) + 4*q + (j&3)];
            wL2[4*p + ks] = as_s8(v);
        }
        bL2v[p] = *(const f32x4*)(gb1 + 16*t + 4*q);
    }
    {
        const int n = 16 * w + c;
        const float* w2r = gw2 + n * 128;
        #pragma unroll
        for (int ks = 0; ks < 4; ++ks) {
            bf16x8 v;
            #pragma unroll
            for (int j = 0; j < 8; ++j)
                v[j] = (__bf16)w2r[32*ks + 16*(j>>2) + 4*q + (j&3)];
            wL3[ks] = as_s8(v);
        }
        bL3v = *(const f32x4*)(gb2 + 16*w + 4*q);
    }

    // ---- ODE state: this wave owns dims 16w+4q+r of batch row c ----
    f32x4 yn = *(const f32x4*)(y0 + (size_t)(row0 + c) * 64 + 16*w + 4*q);

    const float ts0 = ts[0];
    const float dtv = ts[1] - ts[0];

    // dt-scaled Tsit5: e = dt*b, h_s = dt*a_{s+1,s}, g_sj = dt*(a_sj - b_j)
    const float e1 = dtv * 0.09646076681806523f, e2 = dtv * 0.01f;
    const float e3 = dtv * 0.4798896504144996f,  e4 = dtv * 1.379008574103742f;
    const float e5 = dtv * -3.290069515436081f,  e6 = dtv * 2.324710524099774f;
    const float h0 = dtv * 0.161f;
    const float h1 = dtv * 0.335480655492357f;
    const float h2 = dtv * 4.3622954328695815f;
    const float h3 = dtv * -0.09249506636175525f;
    const float h4 = dtv * -0.028269050394068383f;
    const float g31 = dtv * (-0.008480655492356989f - 0.09646076681806523f);
    const float g41 = dtv * (2.8971530571054935f    - 0.09646076681806523f);
    const float g42 = dtv * (-6.359448489975075f    - 0.01f);
    const float g51 = dtv * (5.325864828439257f     - 0.09646076681806523f);
    const float g52 = dtv * (-11.748883564062828f   - 0.01f);
    const float g53 = dtv * (7.4955393428898365f    - 0.4798896504144996f);
    const float g61 = dtv * (5.86145544294642f      - 0.09646076681806523f);
    const float g62 = dtv * (-12.92096931784711f    - 0.01f);
    const float g63 = dtv * (8.159367898576159f     - 0.4798896504144996f);
    const float g64 = dtv * (-0.071584973281401f    - 1.379008574103742f);

    // ---- initial stage input si1 = y0 -> XS; pre for si2 = y0 ----
    *(ushort4v*)(&XS[w >> 1][lane][4 * (w & 1)]) =
        __builtin_bit_cast(ushort4v, pack4(yn));
    f32x4 pre = yn, si, kv;
    __syncthreads();

    #pragma unroll 1
    for (int step = 0; step < NSTEPS; ++step) {
        const float t0s = ts0 + (float)step * dtv;
        bf16x4 kb0, kb1, kb2, kb3;

        // ---- stage 1 ----  (tail after barrier: register-only, overlaps P1)
        STAGE(t0s, h0)
        #pragma unroll
        for (int r = 0; r < 4; ++r) yn[r] += e1 * kv[r];
        kb0 = pack4(kv);
        #pragma unroll
        for (int r = 0; r < 4; ++r) pre[r] = yn[r] + g31 * (float)kb0[r];

        // ---- stage 2 ----
        STAGE(t0s + 0.161f * dtv, h1)
        #pragma unroll
        for (int r = 0; r < 4; ++r) yn[r] += e2 * kv[r];
        kb1 = pack4(kv);
        #pragma unroll
        for (int r = 0; r < 4; ++r)
            pre[r] = yn[r] + g41 * (float)kb0[r] + g42 * (float)kb1[r];

        // ---- stage 3 ----
        STAGE(t0s + 0.327f * dtv, h2)
        #pragma unroll
        for (int r = 0; r < 4; ++r) yn[r] += e3 * kv[r];
        kb2 = pack4(kv);
        #pragma unroll
        for (int r = 0; r < 4; ++r)
            pre[r] = yn[r] + g51 * (float)kb0[r] + g52 * (float)kb1[r]
                   + g53 * (float)kb2[r];

        // ---- stage 4 ----
        STAGE(t0s + 0.9f * dtv, h3)
        #pragma unroll
        for (int r = 0; r < 4; ++r) yn[r] += e4 * kv[r];
        kb3 = pack4(kv);
        #pragma unroll
        for (int r = 0; r < 4; ++r)
            pre[r] = yn[r] + g61 * (float)kb0[r] + g62 * (float)kb1[r]
                   + g63 * (float)kb2[r] + g64 * (float)kb3[r];

        // ---- stage 5 ----
        STAGE(t0s + 0.9800255409045097f * dtv, h4)
        #pragma unroll
        for (int r = 0; r < 4; ++r) { yn[r] += e5 * kv[r]; pre[r] = yn[r]; }

        // ---- stage 6: si = yn + e6*kv = new y (exact f32 carry) ----
        STAGE(t0s + dtv, e6)
        #pragma unroll
        for (int r = 0; r < 4; ++r) { yn[r] = si[r]; pre[r] = si[r]; }
    }

    // ---- output: this wave's dims of row c ----
    *(f32x4*)(&out[(size_t)(row0 + c) * 64 + 16*w + 4*q]) = yn;
}

extern "C" void kernel_launch(void* const* d_in, const int* in_sizes, int n_in,
                              void* d_out, int out_size, void* d_ws, size_t ws_size,
                              hipStream_t stream) {
    const float* y0 = (const float*)d_in[0];
    const float* ts = (const float*)d_in[1];
    const float* w0 = (const float*)d_in[2];
    const float* b0 = (const float*)d_in[3];
    const float* w1 = (const float*)d_in[4];
    const float* b1 = (const float*)d_in[5];
    const float* w2 = (const float*)d_in[6];
    const float* b2 = (const float*)d_in[7];
    float* out = (float*)d_out;

    node_solve<<<dim3(128), dim3(256), 0, stream>>>(y0, ts, w0, b0, w1, b1, w2, b2, out);
}